// Round 16
// baseline (363.354 us; speedup 1.0000x reference)
//
#include <hip/hip_runtime.h>
#include <stdint.h>

#define B_TOK 32768
#define DM 1024
#define NEXP 16
#define RK 64
#define NPAIR 256
#define TPT 64            // tokens per combine (pair) tile
#define HT 128            // assignments per hidden (expert) tile
#define GRID_CMB 3072     // (tiles x 4 d-chunks), %8==0
#define GRID_HID 544      // >= 512 + 16 worst case, %8==0
#define MAXTILE 1024

typedef unsigned short u16;
typedef __bf16 bf16x8 __attribute__((ext_vector_type(8)));
typedef float f32x4 __attribute__((ext_vector_type(4)));

__device__ __forceinline__ u16 f2bf(float f) {
  union { float f; uint32_t u; } v; v.f = f;
  return (u16)((v.u + 0x7fffu + ((v.u >> 16) & 1u)) >> 16);
}
__device__ __forceinline__ float bf2f(u16 u) {
  union { uint32_t i; float f; } v; v.i = ((uint32_t)u) << 16; return v.f;
}

__device__ __forceinline__ void gload_lds16(const void* g, void* l) {
  __builtin_amdgcn_global_load_lds(
      (const __attribute__((address_space(1))) void*)g,
      (__attribute__((address_space(3))) void*)l, 16, 0, 0);
}

// ---------------- fused f32 -> bf16 conversion for We, U, V (each 1M floats) ----------------
__global__ void k_convert3(const float* __restrict__ s0, u16* __restrict__ d0,
                           const float* __restrict__ s1, u16* __restrict__ d1,
                           const float* __restrict__ s2, u16* __restrict__ d2) {
  const int seg = blockIdx.x >> 8;
  const int bid = blockIdx.x & 255;
  const float* src = (seg == 0) ? s0 : (seg == 1) ? s1 : s2;
  u16* dst = (seg == 0) ? d0 : (seg == 1) ? d1 : d2;
  int i = bid * 256 + threadIdx.x;
  #pragma unroll
  for (int v = 0; v < 4; ++v) {
    int idx = i + v * 65536;
    float4 f = reinterpret_cast<const float4*>(src)[idx];
    ushort4 o;
    o.x = f2bf(f.x); o.y = f2bf(f.y); o.z = f2bf(f.z); o.w = f2bf(f.w);
    reinterpret_cast<ushort4*>(dst)[idx] = o;
  }
}

// ---------------- fused gating matrix: Wg_eff = Wg @ We, gbias = Wg @ be ----------------
__global__ void k_wgeff(const float* __restrict__ Wg, const float* __restrict__ We,
                        const float* __restrict__ be,
                        float* __restrict__ Wgeff, float* __restrict__ gbias) {
  int e = blockIdx.y;
  int d = blockIdx.x * 256 + threadIdx.x;
  double acc = 0.0;
  for (int k = 0; k < DM; ++k)
    acc += (double)Wg[e * DM + k] * (double)We[k * DM + d];
  Wgeff[e * DM + d] = (float)acc;
  if (blockIdx.x == 0 && threadIdx.x == 0) {
    double s = 0.0;
    for (int k = 0; k < DM; ++k) s += (double)be[k] * (double)Wg[e * DM + k];
    gbias[e] = (float)s;
  }
}

// ---------------- gating: tiled LDS GEMM (f64 acc) + fused x->bf16 + top-2 ----------------
#define GT 64
#define GD 128

__global__ __launch_bounds__(256) void k_gating(
    const float* __restrict__ x, u16* __restrict__ x_bf,
    const float* __restrict__ Wgeff, const float* __restrict__ gbias,
    const float* __restrict__ gamma,
    int* __restrict__ tk_pid, float* __restrict__ tk_w0, float* __restrict__ tk_w1,
    int* __restrict__ counts_p, int* __restrict__ counts_e) {
  __shared__ float xs[GT][GD + 4];
  __shared__ float wsd[NEXP][GD + 4];
  __shared__ float lg[GT][NEXP + 2];
  __shared__ int bcnt[NPAIR];
  __shared__ int bexp[NEXP];
  const int tid = threadIdx.x;
  const int tok0 = blockIdx.x * GT;
  const int t0 = (tid >> 3) * 2;
  const int e0 = (tid & 7) * 2;
  bcnt[tid] = 0;
  if (tid < NEXP) bexp[tid] = 0;

  double acc00 = 0.0, acc01 = 0.0, acc10 = 0.0, acc11 = 0.0;

  for (int c = 0; c < DM; c += GD) {
    __syncthreads();
    #pragma unroll
    for (int v = 0; v < (GT * GD / 4) / 256; ++v) {
      int idx = tid + v * 256;
      int r = idx >> 5, cc = idx & 31;
      float4 v4 = *reinterpret_cast<const float4*>(x + (size_t)(tok0 + r) * DM + c + cc * 4);
      *reinterpret_cast<float4*>(&xs[r][cc * 4]) = v4;
      ushort4 o;
      o.x = f2bf(v4.x); o.y = f2bf(v4.y); o.z = f2bf(v4.z); o.w = f2bf(v4.w);
      *reinterpret_cast<ushort4*>(x_bf + (size_t)(tok0 + r) * DM + c + cc * 4) = o;
    }
    #pragma unroll
    for (int v = 0; v < (NEXP * GD / 4) / 256; ++v) {
      int idx = tid + v * 256;
      int r = idx >> 5, cc = idx & 31;
      *reinterpret_cast<float4*>(&wsd[r][cc * 4]) =
          *reinterpret_cast<const float4*>(Wgeff + (size_t)r * DM + c + cc * 4);
    }
    __syncthreads();
    #pragma unroll 8
    for (int d = 0; d < GD; d += 4) {
      float4 xa = *reinterpret_cast<const float4*>(&xs[t0][d]);
      float4 xb = *reinterpret_cast<const float4*>(&xs[t0 + 1][d]);
      float4 wa = *reinterpret_cast<const float4*>(&wsd[e0][d]);
      float4 wb = *reinterpret_cast<const float4*>(&wsd[e0 + 1][d]);
      acc00 += (double)xa.x * wa.x + (double)xa.y * wa.y + (double)xa.z * wa.z + (double)xa.w * wa.w;
      acc01 += (double)xa.x * wb.x + (double)xa.y * wb.y + (double)xa.z * wb.z + (double)xa.w * wb.w;
      acc10 += (double)xb.x * wa.x + (double)xb.y * wa.y + (double)xb.z * wa.z + (double)xb.w * wa.w;
      acc11 += (double)xb.x * wb.x + (double)xb.y * wb.y + (double)xb.z * wb.z + (double)xb.w * wb.w;
    }
  }

  lg[t0][e0]         = (float)(acc00 + (double)gbias[e0]);
  lg[t0][e0 + 1]     = (float)(acc01 + (double)gbias[e0 + 1]);
  lg[t0 + 1][e0]     = (float)(acc10 + (double)gbias[e0]);
  lg[t0 + 1][e0 + 1] = (float)(acc11 + (double)gbias[e0 + 1]);
  __syncthreads();

  if (tid < GT) {
    int tok = tok0 + tid;
    float v0 = lg[tid][0]; int i0 = 0;
    #pragma unroll
    for (int j = 1; j < NEXP; ++j)
      if (lg[tid][j] > v0) { v0 = lg[tid][j]; i0 = j; }
    float v1 = -3.4e38f; int i1 = 0;
    #pragma unroll
    for (int j = 0; j < NEXP; ++j) {
      if (j == i0) continue;
      if (lg[tid][j] > v1) { v1 = lg[tid][j]; i1 = j; }
    }
    float e1 = expf(v1 - v0);
    float denom = 1.0f + e1 + 1e-12f;
    float w0 = 1.0f / denom, w1 = e1 / denom;
    if (!(w0 > 1e-12f)) w0 = 0.0f;
    if (!(w1 > 1e-12f)) w1 = 0.0f;
    int pid = i0 * 16 + i1;
    tk_pid[tok] = pid;
    tk_w0[tok] = w0 * gamma[i0];
    tk_w1[tok] = w1 * gamma[i1];
    atomicAdd(&bcnt[pid], 1);
    atomicAdd(&bexp[i0], 1);
    atomicAdd(&bexp[i1], 1);
  }
  __syncthreads();
  if (bcnt[tid] > 0) atomicAdd(&counts_p[tid], bcnt[tid]);
  if (tid < NEXP && bexp[tid] > 0) atomicAdd(&counts_e[tid], bexp[tid]);
}

// ---------------- scans + tile tables (pairs for combine, experts for hidden) ----------------
__global__ __launch_bounds__(NPAIR) void k_scan(
    const int* __restrict__ counts_p, const int* __restrict__ counts_e,
    int* __restrict__ offs_p, int* __restrict__ curs_p,
    int* __restrict__ offs_e, int* __restrict__ curs_e,
    int* __restrict__ tp_pair, int* __restrict__ tp_loc, int* __restrict__ n_tp,
    int* __restrict__ th_exp, int* __restrict__ th_loc, int* __restrict__ n_th) {
  __shared__ int sc[NPAIR], st[NPAIR];
  __shared__ int seb[NEXP + 1], thb[NEXP + 1];
  const int tid = threadIdx.x;
  const int c = counts_p[tid];
  const int nt = (c + TPT - 1) / TPT;
  sc[tid] = c; st[tid] = nt;
  __syncthreads();
  for (int s = 1; s < NPAIR; s <<= 1) {
    int vc = 0, vt = 0;
    if (tid >= s) { vc = sc[tid - s]; vt = st[tid - s]; }
    __syncthreads();
    sc[tid] += vc; st[tid] += vt;
    __syncthreads();
  }
  const int offc = sc[tid] - c;
  const int offt = st[tid] - nt;
  offs_p[tid] = offc;
  curs_p[tid] = offc;
  if (tid == NPAIR - 1) { offs_p[NPAIR] = sc[tid]; n_tp[0] = st[tid]; }
  for (int q = 0; q < nt; ++q) { tp_pair[offt + q] = tid; tp_loc[offt + q] = q * TPT; }

  if (tid == 0) {
    int s = 0, s2 = 0;
    for (int e = 0; e < NEXP; ++e) {
      seb[e] = s; thb[e] = s2;
      int ce = counts_e[e];
      s += ce; s2 += (ce + HT - 1) / HT;
    }
    seb[NEXP] = s; thb[NEXP] = s2;
    n_th[0] = s2;
  }
  __syncthreads();
  if (tid <= NEXP) offs_e[tid] = seb[tid];
  if (tid < NEXP) {
    curs_e[tid] = seb[tid];
    int ce = counts_e[tid];
    int ntt = (ce + HT - 1) / HT;
    for (int q = 0; q < ntt; ++q) { th_exp[thb[tid] + q] = tid; th_loc[thb[tid] + q] = q * HT; }
  }
}

// ---------------- scatter: LDS-aggregated ranks + pair-slot map for H layout ----------------
// h2p[expert_list_pos] = 2*pair_pos + side : hidden writes H in PAIR-LIST order so
// combine's H reads are a contiguous window.
__global__ __launch_bounds__(256) void k_scatter(
    const int* __restrict__ tk_pid, const float* __restrict__ tk_w0,
    const float* __restrict__ tk_w1,
    int* __restrict__ curs_p, int* __restrict__ curs_e,
    int* __restrict__ a_tok, int* __restrict__ h2p,
    int* __restrict__ e_tok, float* __restrict__ e_w) {
  __shared__ int hp[NPAIR];   // pair histogram
  __shared__ int he[NEXP];    // expert histogram
  __shared__ int bp[NPAIR];   // pair block base
  __shared__ int beB[NEXP];   // expert block base
  const int tid = threadIdx.x;
  const int tok = blockIdx.x * 256 + tid;
  hp[tid] = 0;
  if (tid < NEXP) he[tid] = 0;
  __syncthreads();

  const int pid = tk_pid[tok];
  const int i0 = pid >> 4, i1 = pid & 15;
  const int rp = atomicAdd(&hp[pid], 1);   // LDS atomics -> in-block rank
  const int r0 = atomicAdd(&he[i0], 1);
  const int r1 = atomicAdd(&he[i1], 1);
  __syncthreads();

  if (hp[tid] > 0) bp[tid] = atomicAdd(&curs_p[tid], hp[tid]);
  if (tid < NEXP && he[tid] > 0) beB[tid] = atomicAdd(&curs_e[tid], he[tid]);
  __syncthreads();

  const int posp = bp[pid] + rp;
  const int pos0 = beB[i0] + r0;
  const int pos1 = beB[i1] + r1;
  a_tok[posp] = tok;
  h2p[pos0] = posp * 2;
  h2p[pos1] = posp * 2 + 1;
  e_tok[pos0] = tok; e_w[pos0] = tk_w0[tok];
  e_tok[pos1] = tok; e_w[pos1] = tk_w1[tok];
}

// ---------------- encoder GEMM: enc_bf = bf16(x @ We^T + be), XCD-swizzled ----------------
// BK=64, conflict-free 8-chunk XOR swizzle + 2-phase counted-vmcnt double buffer.
__global__ __launch_bounds__(256) void k_encoder(
    const u16* __restrict__ A, const u16* __restrict__ Bm,
    const float* __restrict__ bias, u16* __restrict__ Cb) {
  __shared__ __align__(16) u16 As0[128 * 64];
  __shared__ __align__(16) u16 Bs0[128 * 64];
  __shared__ __align__(16) u16 As1[128 * 64];
  __shared__ __align__(16) u16 Bs1[128 * 64];
  const int nwg = gridDim.x * gridDim.y;
  const int orig = blockIdx.y * gridDim.x + blockIdx.x;
  const int qq = nwg >> 3;
  const int swz = (orig & 7) * qq + (orig >> 3);
  const int m0 = (swz / gridDim.x) * 128, n0 = (swz % gridDim.x) * 128;
  const int tid = threadIdx.x;
  const int lane = tid & 63, wave = tid >> 6;
  const int wr = wave >> 1, wc = wave & 1;
  const int lrow = lane & 15, lhi = lane >> 4;

  f32x4 acc[4][4];
  #pragma unroll
  for (int i = 0; i < 4; ++i)
    #pragma unroll
    for (int j = 0; j < 4; ++j) acc[i][j] = (f32x4){0.f, 0.f, 0.f, 0.f};

  const u16* gA0; const u16* gA1; const u16* gA2; const u16* gA3;
  const u16* gB0; const u16* gB1; const u16* gB2; const u16* gB3;
  int dOf0, dOf1, dOf2, dOf3;
  {
    int slot, row, c, sc;
    slot = tid;         row = slot >> 3; c = slot & 7; sc = (c ^ (row & 7)) * 8;
    gA0 = A + (size_t)(m0 + row) * DM + sc; gB0 = Bm + (size_t)(n0 + row) * DM + sc; dOf0 = slot * 8;
    slot = tid + 256;   row = slot >> 3; c = slot & 7; sc = (c ^ (row & 7)) * 8;
    gA1 = A + (size_t)(m0 + row) * DM + sc; gB1 = Bm + (size_t)(n0 + row) * DM + sc; dOf1 = slot * 8;
    slot = tid + 512;   row = slot >> 3; c = slot & 7; sc = (c ^ (row & 7)) * 8;
    gA2 = A + (size_t)(m0 + row) * DM + sc; gB2 = Bm + (size_t)(n0 + row) * DM + sc; dOf2 = slot * 8;
    slot = tid + 768;   row = slot >> 3; c = slot & 7; sc = (c ^ (row & 7)) * 8;
    gA3 = A + (size_t)(m0 + row) * DM + sc; gB3 = Bm + (size_t)(n0 + row) * DM + sc; dOf3 = slot * 8;
  }

  const int rk0 = ((0 + lhi) ^ (lrow & 7)) * 8;
  const int rk1 = ((4 + lhi) ^ (lrow & 7)) * 8;

  auto STAGE = [&](u16* Ad, u16* Bd, int k0) {
    gload_lds16(gA0 + k0, Ad + dOf0);
    gload_lds16(gA1 + k0, Ad + dOf1);
    gload_lds16(gA2 + k0, Ad + dOf2);
    gload_lds16(gA3 + k0, Ad + dOf3);
    gload_lds16(gB0 + k0, Bd + dOf0);
    gload_lds16(gB1 + k0, Bd + dOf1);
    gload_lds16(gB2 + k0, Bd + dOf2);
    gload_lds16(gB3 + k0, Bd + dOf3);
  };
  auto COMPUTE = [&](const u16* Ar, const u16* Br) {
    #pragma unroll
    for (int kk = 0; kk < 2; ++kk) {
      const int rk = kk ? rk1 : rk0;
      bf16x8 a[4], b[4];
      #pragma unroll
      for (int mi = 0; mi < 4; ++mi)
        a[mi] = *reinterpret_cast<const bf16x8*>(&Ar[(wr * 64 + mi * 16 + lrow) * 64 + rk]);
      #pragma unroll
      for (int nj = 0; nj < 4; ++nj)
        b[nj] = *reinterpret_cast<const bf16x8*>(&Br[(wc * 64 + nj * 16 + lrow) * 64 + rk]);
      #pragma unroll
      for (int mi = 0; mi < 4; ++mi)
        #pragma unroll
        for (int nj = 0; nj < 4; ++nj)
          acc[mi][nj] = __builtin_amdgcn_mfma_f32_16x16x32_bf16(a[mi], b[nj], acc[mi][nj], 0, 0, 0);
    }
  };

  STAGE(As0, Bs0, 0);
  #pragma unroll
  for (int i = 0; i < 8; ++i) {
    STAGE(As1, Bs1, i * 128 + 64);
    asm volatile("s_waitcnt vmcnt(8)" ::: "memory");
    __builtin_amdgcn_s_barrier();
    COMPUTE(As0, Bs0);
    __builtin_amdgcn_s_barrier();
    if (i < 7) {
      STAGE(As0, Bs0, i * 128 + 128);
      asm volatile("s_waitcnt vmcnt(8)" ::: "memory");
    } else {
      asm volatile("s_waitcnt vmcnt(0)" ::: "memory");
    }
    __builtin_amdgcn_s_barrier();
    COMPUTE(As1, Bs1);
    __builtin_amdgcn_s_barrier();
  }

  const int orow = lhi * 4, ocol = lrow;
  #pragma unroll
  for (int mi = 0; mi < 4; ++mi) {
    #pragma unroll
    for (int nj = 0; nj < 4; ++nj) {
      int gcol = n0 + wc * 64 + nj * 16 + ocol;
      float bv = bias[gcol];
      #pragma unroll
      for (int r = 0; r < 4; ++r) {
        int grow = m0 + wr * 64 + mi * 16 + orow + r;
        Cb[(size_t)grow * DM + gcol] = f2bf(acc[mi][nj][r] + bv);
      }
    }
  }
}

// ---------------- hidden kernel: Hp[pairslot][64] = silu(enc @ U_e^T) * w ----------------
// Writes through h2p (pair-list order) so combine reads a contiguous window.
__global__ __launch_bounds__(256) void k_hidden(
    const u16* __restrict__ Enc, const u16* __restrict__ Ub,
    const int* __restrict__ offs_e, const int* __restrict__ th_exp,
    const int* __restrict__ th_loc, const int* __restrict__ n_th,
    const int* __restrict__ e_tok, const float* __restrict__ e_w,
    const int* __restrict__ h2p, u16* __restrict__ Hp) {
  const int bswz = (blockIdx.x & 7) * (GRID_HID >> 3) + (blockIdx.x >> 3);
  if (bswz >= n_th[0]) return;
  const int e = th_exp[bswz];
  const int loc0 = th_loc[bswz];
  const int base = offs_e[e];
  const int cnt = offs_e[e + 1] - base;
  const int tid = threadIdx.x;
  const int lane = tid & 63, wave = tid >> 6;
  const int lrow = lane & 15;
  const int lkb = (lane >> 4) * 16;  // byte offset of k-chunk within 64B

  __shared__ float s_ew[HT];
  __shared__ int s_hp[HT];
  __shared__ __align__(16) u16 Us[64 * 512];  // 64 KB: one K-half of U_e
  if (tid < HT) {
    int i = loc0 + tid;
    int v = i < cnt;
    s_ew[tid] = v ? e_w[base + i] : 0.0f;
    s_hp[tid] = v ? h2p[base + i] : 0;
  }

  const u16* aP[2];
  #pragma unroll
  for (int mi = 0; mi < 2; ++mi) {
    int ridx = loc0 + wave * 32 + mi * 16 + lrow;
    int v = ridx < cnt;
    int tok = e_tok[base + (v ? ridx : 0)];
    aP[mi] = Enc + (size_t)tok * DM + (lane >> 4) * 8;
  }

  f32x4 acc[2][4];
  #pragma unroll
  for (int i = 0; i < 2; ++i)
    #pragma unroll
    for (int j = 0; j < 4; ++j) acc[i][j] = (f32x4){0.f, 0.f, 0.f, 0.f};

  const char* Ue = (const char*)(Ub + (size_t)e * RK * DM);  // row stride 2048 B

  for (int half = 0; half < 2; ++half) {
    __syncthreads();
    #pragma unroll
    for (int it = 0; it < 16; ++it) {
      int D = (tid + it * 256) * 16;
      int row = D >> 10, bo = D & 1023;
      int sbo = bo ^ ((row & 7) << 4);
      gload_lds16(Ue + (size_t)row * 2048 + half * 1024 + sbo, ((char*)Us) + D);
    }
    __syncthreads();
    #pragma unroll 4
    for (int step = 0; step < 16; ++step) {
      const int k0 = half * 512 + step * 32;
      bf16x8 b[4];
      #pragma unroll
      for (int nj = 0; nj < 4; ++nj) {
        int n = nj * 16 + lrow;
        int bofs = n * 1024 + ((step * 64 + lkb) ^ ((n & 7) << 4));
        b[nj] = *reinterpret_cast<const bf16x8*>(((const char*)Us) + bofs);
      }
      bf16x8 a0 = *reinterpret_cast<const bf16x8*>(aP[0] + k0);
      bf16x8 a1 = *reinterpret_cast<const bf16x8*>(aP[1] + k0);
      #pragma unroll
      for (int nj = 0; nj < 4; ++nj) {
        acc[0][nj] = __builtin_amdgcn_mfma_f32_16x16x32_bf16(a0, b[nj], acc[0][nj], 0, 0, 0);
        acc[1][nj] = __builtin_amdgcn_mfma_f32_16x16x32_bf16(a1, b[nj], acc[1][nj], 0, 0, 0);
      }
    }
  }

  #pragma unroll
  for (int mi = 0; mi < 2; ++mi)
    #pragma unroll
    for (int nj = 0; nj < 4; ++nj)
      #pragma unroll
      for (int rr = 0; rr < 4; ++rr) {
        int rloc = wave * 32 + mi * 16 + (lane >> 4) * 4 + rr;
        if (loc0 + rloc < cnt) {
          float z = acc[mi][nj][rr];
          float h = z / (1.0f + expf(-z)) * s_ew[rloc];
          Hp[(size_t)s_hp[rloc] * RK + nj * 16 + (lane & 15)] = f2bf(h);
        }
      }
}

// ---------------- combine kernel: Out[tok] = enc + V0 @ H0 + V1 @ H1 ----------------
// Grid = tiles x 4 d-chunks. H reads are contiguous (pair-ordered Hp); T14 enc prefetch.
__global__ __launch_bounds__(256) void k_combine(
    const u16* __restrict__ Enc, const u16* __restrict__ Vb,
    const u16* __restrict__ Hp, const int* __restrict__ offs_p,
    const int* __restrict__ tp_pair, const int* __restrict__ tp_loc,
    const int* __restrict__ n_tp, const int* __restrict__ a_tok,
    float* __restrict__ Out) {
  const int bswz = (blockIdx.x & 7) * (GRID_CMB >> 3) + (blockIdx.x >> 3);
  const int t = bswz >> 2;
  const int p = bswz & 3;
  if (t >= n_tp[0]) return;
  const int pid = tp_pair[t];
  const int pe0 = pid >> 4, pe1 = pid & 15;
  const int base = offs_p[pid];
  const int cnt = offs_p[pid + 1] - base;
  const int loc0 = tp_loc[t];
  const int tid = threadIdx.x;
  const int lane = tid & 63, wave = tid >> 6;

  __shared__ int s_tok[TPT];
  __shared__ int s_val[TPT];
  if (tid < TPT) {
    int idx = loc0 + tid;
    int v = idx < cnt;
    int pp = base + (v ? idx : 0);
    s_val[tid] = v;
    s_tok[tid] = a_tok[pp];
  }
  __syncthreads();

  const int lrow = lane & 15, lk = (lane >> 4) * 8;
  const int col0 = p * 256 + wave * 64;

  // H fragments: contiguous pair-ordered rows (base+loc0+tok)*2 + side
  bf16x8 hb[4][4];  // [kk][tf]
  #pragma unroll
  for (int kk = 0; kk < 4; ++kk)
    #pragma unroll
    for (int tf = 0; tf < 4; ++tf) {
      int tok = tf * 16 + lrow;
      size_t hrow = (size_t)(base + loc0 + tok) * 2 + (kk < 2 ? 0 : 1);
      hb[kk][tf] = *reinterpret_cast<const bf16x8*>(
          Hp + hrow * RK + (kk & 1) * 32 + lk);
    }

  // T14: enc prefetch — issued before the V/MFMA phase, consumed in epilogue
  ushort4 encv[4][4];  // [mi][tf]
  #pragma unroll
  for (int mi = 0; mi < 4; ++mi)
    #pragma unroll
    for (int tf = 0; tf < 4; ++tf) {
      int tok = tf * 16 + (lane & 15);
      int d = col0 + mi * 16 + (lane >> 4) * 4;
      encv[mi][tf] = *reinterpret_cast<const ushort4*>(Enc + (size_t)s_tok[tok] * DM + d);
    }

  const u16* V0 = Vb + (size_t)pe0 * DM * RK;
  const u16* V1 = Vb + (size_t)pe1 * DM * RK;

  f32x4 acc2[4][4];  // [mi][tf]
  #pragma unroll
  for (int i = 0; i < 4; ++i)
    #pragma unroll
    for (int j = 0; j < 4; ++j) acc2[i][j] = (f32x4){0.f, 0.f, 0.f, 0.f};

  #pragma unroll
  for (int kk = 0; kk < 4; ++kk) {
    const u16* Vsel = (kk < 2) ? V0 : V1;
    const int kof = (kk & 1) * 32 + lk;
    #pragma unroll
    for (int mi = 0; mi < 4; ++mi) {
      int d = col0 + mi * 16 + lrow;
      bf16x8 va = *reinterpret_cast<const bf16x8*>(Vsel + (size_t)d * RK + kof);
      #pragma unroll
      for (int tf = 0; tf < 4; ++tf)
        acc2[mi][tf] = __builtin_amdgcn_mfma_f32_16x16x32_bf16(va, hb[kk][tf], acc2[mi][tf], 0, 0, 0);
    }
  }

  #pragma unroll
  for (int mi = 0; mi < 4; ++mi)
    #pragma unroll
    for (int tf = 0; tf < 4; ++tf) {
      int tok = tf * 16 + (lane & 15);
      if (!s_val[tok]) continue;
      int d = col0 + mi * 16 + (lane >> 4) * 4;
      size_t ro = (size_t)s_tok[tok] * DM + d;
      ushort4 ev = encv[mi][tf];
      float4 o;
      o.x = acc2[mi][tf][0] + bf2f(ev.x);
      o.y = acc2[mi][tf][1] + bf2f(ev.y);
      o.z = acc2[mi][tf][2] + bf2f(ev.z);
      o.w = acc2[mi][tf][3] + bf2f(ev.w);
      *reinterpret_cast<float4*>(Out + ro) = o;
    }
}

// ---------------- host launch ----------------
extern "C" void kernel_launch(void* const* d_in, const int* in_sizes, int n_in,
                              void* d_out, int out_size, void* d_ws, size_t ws_size,
                              hipStream_t stream) {
  const float* x = (const float*)d_in[0];
  const float* We = (const float*)d_in[1];
  const float* be = (const float*)d_in[2];
  const float* Wg = (const float*)d_in[3];
  const float* U = (const float*)d_in[4];
  const float* V = (const float*)d_in[5];
  const float* gamma = (const float*)d_in[6];
  float* Out = (float*)d_out;

  char* ws = (char*)d_ws;
  size_t off = 0;
  auto alloc = [&](size_t bytes) -> void* {
    void* p = ws + off;
    off += (bytes + 255) & ~(size_t)255;
    return p;
  };
  u16* x_bf   = (u16*)alloc((size_t)B_TOK * DM * 2);
  u16* enc_bf = (u16*)alloc((size_t)B_TOK * DM * 2);
  u16* We_bf  = (u16*)alloc((size_t)DM * DM * 2);
  u16* U_bf   = (u16*)alloc((size_t)NEXP * RK * DM * 2);
  u16* V_bf   = (u16*)alloc((size_t)NEXP * DM * RK * 2);
  u16* Hp     = (u16*)alloc((size_t)2 * (B_TOK + TPT) * RK * 2);
  float* Wgeff = (float*)alloc((size_t)NEXP * DM * 4);
  float* gbias = (float*)alloc(NEXP * 4);
  int* tk_pid  = (int*)alloc((size_t)B_TOK * 4);
  float* tk_w0 = (float*)alloc((size_t)B_TOK * 4);
  float* tk_w1 = (float*)alloc((size_t)B_TOK * 4);
  int* counts_p = (int*)alloc(NPAIR * 4);
  int* counts_e = (int*)alloc(NEXP * 4);
  int* offs_p   = (int*)alloc((NPAIR + 1) * 4);
  int* curs_p   = (int*)alloc(NPAIR * 4);
  int* offs_e   = (int*)alloc((NEXP + 1) * 4);
  int* curs_e   = (int*)alloc(NEXP * 4);
  int* tp_pair  = (int*)alloc(MAXTILE * 4);
  int* tp_loc   = (int*)alloc(MAXTILE * 4);
  int* n_tp     = (int*)alloc(256);
  int* th_exp   = (int*)alloc(MAXTILE * 4);
  int* th_loc   = (int*)alloc(MAXTILE * 4);
  int* n_th     = (int*)alloc(256);
  int* a_tok   = (int*)alloc((size_t)B_TOK * 4);
  int* h2p     = (int*)alloc(((size_t)2 * B_TOK + HT) * 4);
  int* e_tok   = (int*)alloc(((size_t)2 * B_TOK + HT) * 4);
  float* e_w   = (float*)alloc(((size_t)2 * B_TOK + HT) * 4);
  (void)ws_size; (void)in_sizes; (void)n_in; (void)out_size;

  hipMemsetAsync(counts_p, 0, NPAIR * 4, stream);
  hipMemsetAsync(counts_e, 0, NEXP * 4, stream);

  k_convert3<<<768, 256, 0, stream>>>(We, We_bf, U, U_bf, V, V_bf);
  k_wgeff<<<dim3(4, 16), 256, 0, stream>>>(Wg, We, be, Wgeff, gbias);
  k_gating<<<B_TOK / GT, 256, 0, stream>>>(x, x_bf, Wgeff, gbias, gamma,
                                           tk_pid, tk_w0, tk_w1, counts_p, counts_e);
  k_scan<<<1, NPAIR, 0, stream>>>(counts_p, counts_e, offs_p, curs_p, offs_e, curs_e,
                                  tp_pair, tp_loc, n_tp, th_exp, th_loc, n_th);
  k_scatter<<<B_TOK / 256, 256, 0, stream>>>(tk_pid, tk_w0, tk_w1, curs_p, curs_e,
                                             a_tok, h2p, e_tok, e_w);
  k_encoder<<<dim3(DM / 128, B_TOK / 128), 256, 0, stream>>>(x_bf, We_bf, be, enc_bf);
  k_hidden<<<GRID_HID, 256, 0, stream>>>(enc_bf, U_bf, offs_e, th_exp, th_loc, n_th,
                                         e_tok, e_w, h2p, Hp);
  k_combine<<<GRID_CMB, 256, 0, stream>>>(enc_bf, V_bf, Hp, offs_p, tp_pair, tp_loc,
                                          n_tp, a_tok, Out);
}

// Round 17
// 320.685 us; speedup vs baseline: 1.1331x; 1.1331x over previous
//
#include <hip/hip_runtime.h>
#include <stdint.h>

#define B_TOK 32768
#define DM 1024
#define NEXP 16
#define RK 64
#define NPAIR 256
#define TPT 64            // tokens per combine (pair) tile
#define HT 128            // assignments per hidden (expert) tile
#define GRID_CMB 3072     // (tiles x 4 d-chunks), %8==0
#define GRID_HID 544      // >= 512 + 16 worst case, %8==0
#define MAXTILE 1024

typedef unsigned short u16;
typedef __bf16 bf16x8 __attribute__((ext_vector_type(8)));
typedef float f32x4 __attribute__((ext_vector_type(4)));

__device__ __forceinline__ u16 f2bf(float f) {
  union { float f; uint32_t u; } v; v.f = f;
  return (u16)((v.u + 0x7fffu + ((v.u >> 16) & 1u)) >> 16);
}
__device__ __forceinline__ float bf2f(u16 u) {
  union { uint32_t i; float f; } v; v.i = ((uint32_t)u) << 16; return v.f;
}

__device__ __forceinline__ void gload_lds16(const void* g, void* l) {
  __builtin_amdgcn_global_load_lds(
      (const __attribute__((address_space(1))) void*)g,
      (__attribute__((address_space(3))) void*)l, 16, 0, 0);
}

// ---------------- prep: f32->bf16 for We/U/V (blocks 0..767) + Wg@We K-partials
// (blocks 768..1023: 4 K-chunks x 16 e x 4 d-blocks, 4 indep accumulators) ----------------
__global__ void k_prep(const float* __restrict__ s0, u16* __restrict__ d0,
                       const float* __restrict__ s1, u16* __restrict__ d1,
                       const float* __restrict__ s2, u16* __restrict__ d2,
                       const float* __restrict__ Wg, const float* __restrict__ We,
                       double* __restrict__ Wpart) {
  const int b = blockIdx.x;
  if (b < 768) {
    const int seg = b >> 8;
    const int bid = b & 255;
    const float* src = (seg == 0) ? s0 : (seg == 1) ? s1 : s2;
    u16* dst = (seg == 0) ? d0 : (seg == 1) ? d1 : d2;
    int i = bid * 256 + threadIdx.x;
    #pragma unroll
    for (int v = 0; v < 4; ++v) {
      int idx = i + v * 65536;
      float4 f = reinterpret_cast<const float4*>(src)[idx];
      ushort4 o;
      o.x = f2bf(f.x); o.y = f2bf(f.y); o.z = f2bf(f.z); o.w = f2bf(f.w);
      reinterpret_cast<ushort4*>(dst)[idx] = o;
    }
  } else {
    const int pb = b - 768;        // 0..255
    const int kc = pb >> 6;        // 0..3
    const int rem = pb & 63;
    const int e = rem >> 2;        // 0..15
    const int bx = rem & 3;        // 0..3
    const int d = bx * 256 + threadIdx.x;
    const int kbase = kc * 256;
    double a0 = 0.0, a1 = 0.0, a2 = 0.0, a3 = 0.0;
    for (int k = 0; k < 256; k += 4) {
      int kk = kbase + k;
      a0 += (double)Wg[e * DM + kk]     * (double)We[(size_t)kk * DM + d];
      a1 += (double)Wg[e * DM + kk + 1] * (double)We[(size_t)(kk + 1) * DM + d];
      a2 += (double)Wg[e * DM + kk + 2] * (double)We[(size_t)(kk + 2) * DM + d];
      a3 += (double)Wg[e * DM + kk + 3] * (double)We[(size_t)(kk + 3) * DM + d];
    }
    Wpart[((size_t)kc * NEXP + e) * DM + d] = (a0 + a1) + (a2 + a3);
  }
}

// ---------------- reduce partials (fixed order, deterministic) + gbias ----------------
__global__ void k_wgred(const double* __restrict__ Wpart, const float* __restrict__ Wg,
                        const float* __restrict__ be,
                        float* __restrict__ Wgeff, float* __restrict__ gbias) {
  const int e = blockIdx.y;
  const int d = blockIdx.x * 256 + threadIdx.x;
  double s = 0.0;
  #pragma unroll
  for (int kc = 0; kc < 4; ++kc)
    s += Wpart[((size_t)kc * NEXP + e) * DM + d];
  Wgeff[e * DM + d] = (float)s;
  if (blockIdx.x == 0 && threadIdx.x == 0) {
    double g = 0.0;
    for (int k = 0; k < DM; ++k) g += (double)be[k] * (double)Wg[e * DM + k];
    gbias[e] = (float)g;
  }
}

// ---------------- gating: tiled LDS GEMM (f64 acc) + fused x->bf16 + top-2 ----------------
#define GT 64
#define GD 128

__global__ __launch_bounds__(256) void k_gating(
    const float* __restrict__ x, u16* __restrict__ x_bf,
    const float* __restrict__ Wgeff, const float* __restrict__ gbias,
    const float* __restrict__ gamma,
    int* __restrict__ tk_pid, float* __restrict__ tk_w0, float* __restrict__ tk_w1,
    int* __restrict__ counts_p, int* __restrict__ counts_e) {
  __shared__ float xs[GT][GD + 4];
  __shared__ float wsd[NEXP][GD + 4];
  __shared__ float lg[GT][NEXP + 2];
  __shared__ int bcnt[NPAIR];
  __shared__ int bexp[NEXP];
  const int tid = threadIdx.x;
  const int tok0 = blockIdx.x * GT;
  const int t0 = (tid >> 3) * 2;
  const int e0 = (tid & 7) * 2;
  bcnt[tid] = 0;
  if (tid < NEXP) bexp[tid] = 0;

  double acc00 = 0.0, acc01 = 0.0, acc10 = 0.0, acc11 = 0.0;

  for (int c = 0; c < DM; c += GD) {
    __syncthreads();
    #pragma unroll
    for (int v = 0; v < (GT * GD / 4) / 256; ++v) {
      int idx = tid + v * 256;
      int r = idx >> 5, cc = idx & 31;
      float4 v4 = *reinterpret_cast<const float4*>(x + (size_t)(tok0 + r) * DM + c + cc * 4);
      *reinterpret_cast<float4*>(&xs[r][cc * 4]) = v4;
      ushort4 o;
      o.x = f2bf(v4.x); o.y = f2bf(v4.y); o.z = f2bf(v4.z); o.w = f2bf(v4.w);
      *reinterpret_cast<ushort4*>(x_bf + (size_t)(tok0 + r) * DM + c + cc * 4) = o;
    }
    #pragma unroll
    for (int v = 0; v < (NEXP * GD / 4) / 256; ++v) {
      int idx = tid + v * 256;
      int r = idx >> 5, cc = idx & 31;
      *reinterpret_cast<float4*>(&wsd[r][cc * 4]) =
          *reinterpret_cast<const float4*>(Wgeff + (size_t)r * DM + c + cc * 4);
    }
    __syncthreads();
    #pragma unroll 8
    for (int d = 0; d < GD; d += 4) {
      float4 xa = *reinterpret_cast<const float4*>(&xs[t0][d]);
      float4 xb = *reinterpret_cast<const float4*>(&xs[t0 + 1][d]);
      float4 wa = *reinterpret_cast<const float4*>(&wsd[e0][d]);
      float4 wb = *reinterpret_cast<const float4*>(&wsd[e0 + 1][d]);
      acc00 += (double)xa.x * wa.x + (double)xa.y * wa.y + (double)xa.z * wa.z + (double)xa.w * wa.w;
      acc01 += (double)xa.x * wb.x + (double)xa.y * wb.y + (double)xa.z * wb.z + (double)xa.w * wb.w;
      acc10 += (double)xb.x * wa.x + (double)xb.y * wa.y + (double)xb.z * wa.z + (double)xb.w * wa.w;
      acc11 += (double)xb.x * wb.x + (double)xb.y * wb.y + (double)xb.z * wb.z + (double)xb.w * wb.w;
    }
  }

  lg[t0][e0]         = (float)(acc00 + (double)gbias[e0]);
  lg[t0][e0 + 1]     = (float)(acc01 + (double)gbias[e0 + 1]);
  lg[t0 + 1][e0]     = (float)(acc10 + (double)gbias[e0]);
  lg[t0 + 1][e0 + 1] = (float)(acc11 + (double)gbias[e0 + 1]);
  __syncthreads();

  if (tid < GT) {
    int tok = tok0 + tid;
    float v0 = lg[tid][0]; int i0 = 0;
    #pragma unroll
    for (int j = 1; j < NEXP; ++j)
      if (lg[tid][j] > v0) { v0 = lg[tid][j]; i0 = j; }
    float v1 = -3.4e38f; int i1 = 0;
    #pragma unroll
    for (int j = 0; j < NEXP; ++j) {
      if (j == i0) continue;
      if (lg[tid][j] > v1) { v1 = lg[tid][j]; i1 = j; }
    }
    float e1 = expf(v1 - v0);
    float denom = 1.0f + e1 + 1e-12f;
    float w0 = 1.0f / denom, w1 = e1 / denom;
    if (!(w0 > 1e-12f)) w0 = 0.0f;
    if (!(w1 > 1e-12f)) w1 = 0.0f;
    int pid = i0 * 16 + i1;
    tk_pid[tok] = pid;
    tk_w0[tok] = w0 * gamma[i0];
    tk_w1[tok] = w1 * gamma[i1];
    atomicAdd(&bcnt[pid], 1);
    atomicAdd(&bexp[i0], 1);
    atomicAdd(&bexp[i1], 1);
  }
  __syncthreads();
  if (bcnt[tid] > 0) atomicAdd(&counts_p[tid], bcnt[tid]);
  if (tid < NEXP && bexp[tid] > 0) atomicAdd(&counts_e[tid], bexp[tid]);
}

// ---------------- scans + tile tables (pairs for combine, experts for hidden) ----------------
__global__ __launch_bounds__(NPAIR) void k_scan(
    const int* __restrict__ counts_p, const int* __restrict__ counts_e,
    int* __restrict__ offs_p, int* __restrict__ curs_p,
    int* __restrict__ offs_e, int* __restrict__ curs_e,
    int* __restrict__ tp_pair, int* __restrict__ tp_loc, int* __restrict__ n_tp,
    int* __restrict__ th_exp, int* __restrict__ th_loc, int* __restrict__ n_th) {
  __shared__ int sc[NPAIR], st[NPAIR];
  __shared__ int seb[NEXP + 1], thb[NEXP + 1];
  const int tid = threadIdx.x;
  const int c = counts_p[tid];
  const int nt = (c + TPT - 1) / TPT;
  sc[tid] = c; st[tid] = nt;
  __syncthreads();
  for (int s = 1; s < NPAIR; s <<= 1) {
    int vc = 0, vt = 0;
    if (tid >= s) { vc = sc[tid - s]; vt = st[tid - s]; }
    __syncthreads();
    sc[tid] += vc; st[tid] += vt;
    __syncthreads();
  }
  const int offc = sc[tid] - c;
  const int offt = st[tid] - nt;
  offs_p[tid] = offc;
  curs_p[tid] = offc;
  if (tid == NPAIR - 1) { offs_p[NPAIR] = sc[tid]; n_tp[0] = st[tid]; }
  for (int q = 0; q < nt; ++q) { tp_pair[offt + q] = tid; tp_loc[offt + q] = q * TPT; }

  if (tid == 0) {
    int s = 0, s2 = 0;
    for (int e = 0; e < NEXP; ++e) {
      seb[e] = s; thb[e] = s2;
      int ce = counts_e[e];
      s += ce; s2 += (ce + HT - 1) / HT;
    }
    seb[NEXP] = s; thb[NEXP] = s2;
    n_th[0] = s2;
  }
  __syncthreads();
  if (tid <= NEXP) offs_e[tid] = seb[tid];
  if (tid < NEXP) {
    curs_e[tid] = seb[tid];
    int ce = counts_e[tid];
    int ntt = (ce + HT - 1) / HT;
    for (int q = 0; q < ntt; ++q) { th_exp[thb[tid] + q] = tid; th_loc[thb[tid] + q] = q * HT; }
  }
}

// ---------------- scatter: LDS-aggregated ranks, one global atomic per bin per block ----------------
__global__ __launch_bounds__(256) void k_scatter(
    const int* __restrict__ tk_pid, const float* __restrict__ tk_w0,
    const float* __restrict__ tk_w1,
    int* __restrict__ curs_p, int* __restrict__ curs_e,
    int* __restrict__ a_tok, int* __restrict__ a_h0,
    int* __restrict__ a_h1,
    int* __restrict__ e_tok, float* __restrict__ e_w) {
  __shared__ int hp[NPAIR];   // pair histogram
  __shared__ int he[NEXP];    // expert histogram
  __shared__ int bp[NPAIR];   // pair block base
  __shared__ int beB[NEXP];   // expert block base
  const int tid = threadIdx.x;
  const int tok = blockIdx.x * 256 + tid;
  hp[tid] = 0;
  if (tid < NEXP) he[tid] = 0;
  __syncthreads();

  const int pid = tk_pid[tok];
  const int i0 = pid >> 4, i1 = pid & 15;
  const int rp = atomicAdd(&hp[pid], 1);   // LDS atomics -> in-block rank
  const int r0 = atomicAdd(&he[i0], 1);
  const int r1 = atomicAdd(&he[i1], 1);
  __syncthreads();

  if (hp[tid] > 0) bp[tid] = atomicAdd(&curs_p[tid], hp[tid]);
  if (tid < NEXP && he[tid] > 0) beB[tid] = atomicAdd(&curs_e[tid], he[tid]);
  __syncthreads();

  const int posp = bp[pid] + rp;
  const int pos0 = beB[i0] + r0;
  const int pos1 = beB[i1] + r1;
  a_tok[posp] = tok;
  a_h0[posp] = pos0;
  a_h1[posp] = pos1;
  e_tok[pos0] = tok; e_w[pos0] = tk_w0[tok];
  e_tok[pos1] = tok; e_w[pos1] = tk_w1[tok];
}

// ---------------- encoder GEMM: enc_bf = bf16(x @ We^T + be), XCD-swizzled ----------------
// BK=64, conflict-free 8-chunk XOR swizzle + 2-phase counted-vmcnt double buffer.
__global__ __launch_bounds__(256) void k_encoder(
    const u16* __restrict__ A, const u16* __restrict__ Bm,
    const float* __restrict__ bias, u16* __restrict__ Cb) {
  __shared__ __align__(16) u16 As0[128 * 64];
  __shared__ __align__(16) u16 Bs0[128 * 64];
  __shared__ __align__(16) u16 As1[128 * 64];
  __shared__ __align__(16) u16 Bs1[128 * 64];
  const int nwg = gridDim.x * gridDim.y;
  const int orig = blockIdx.y * gridDim.x + blockIdx.x;
  const int qq = nwg >> 3;
  const int swz = (orig & 7) * qq + (orig >> 3);
  const int m0 = (swz / gridDim.x) * 128, n0 = (swz % gridDim.x) * 128;
  const int tid = threadIdx.x;
  const int lane = tid & 63, wave = tid >> 6;
  const int wr = wave >> 1, wc = wave & 1;
  const int lrow = lane & 15, lhi = lane >> 4;

  f32x4 acc[4][4];
  #pragma unroll
  for (int i = 0; i < 4; ++i)
    #pragma unroll
    for (int j = 0; j < 4; ++j) acc[i][j] = (f32x4){0.f, 0.f, 0.f, 0.f};

  const u16* gA0; const u16* gA1; const u16* gA2; const u16* gA3;
  const u16* gB0; const u16* gB1; const u16* gB2; const u16* gB3;
  int dOf0, dOf1, dOf2, dOf3;
  {
    int slot, row, c, sc;
    slot = tid;         row = slot >> 3; c = slot & 7; sc = (c ^ (row & 7)) * 8;
    gA0 = A + (size_t)(m0 + row) * DM + sc; gB0 = Bm + (size_t)(n0 + row) * DM + sc; dOf0 = slot * 8;
    slot = tid + 256;   row = slot >> 3; c = slot & 7; sc = (c ^ (row & 7)) * 8;
    gA1 = A + (size_t)(m0 + row) * DM + sc; gB1 = Bm + (size_t)(n0 + row) * DM + sc; dOf1 = slot * 8;
    slot = tid + 512;   row = slot >> 3; c = slot & 7; sc = (c ^ (row & 7)) * 8;
    gA2 = A + (size_t)(m0 + row) * DM + sc; gB2 = Bm + (size_t)(n0 + row) * DM + sc; dOf2 = slot * 8;
    slot = tid + 768;   row = slot >> 3; c = slot & 7; sc = (c ^ (row & 7)) * 8;
    gA3 = A + (size_t)(m0 + row) * DM + sc; gB3 = Bm + (size_t)(n0 + row) * DM + sc; dOf3 = slot * 8;
  }

  const int rk0 = ((0 + lhi) ^ (lrow & 7)) * 8;
  const int rk1 = ((4 + lhi) ^ (lrow & 7)) * 8;

  auto STAGE = [&](u16* Ad, u16* Bd, int k0) {
    gload_lds16(gA0 + k0, Ad + dOf0);
    gload_lds16(gA1 + k0, Ad + dOf1);
    gload_lds16(gA2 + k0, Ad + dOf2);
    gload_lds16(gA3 + k0, Ad + dOf3);
    gload_lds16(gB0 + k0, Bd + dOf0);
    gload_lds16(gB1 + k0, Bd + dOf1);
    gload_lds16(gB2 + k0, Bd + dOf2);
    gload_lds16(gB3 + k0, Bd + dOf3);
  };
  auto COMPUTE = [&](const u16* Ar, const u16* Br) {
    #pragma unroll
    for (int kk = 0; kk < 2; ++kk) {
      const int rk = kk ? rk1 : rk0;
      bf16x8 a[4], b[4];
      #pragma unroll
      for (int mi = 0; mi < 4; ++mi)
        a[mi] = *reinterpret_cast<const bf16x8*>(&Ar[(wr * 64 + mi * 16 + lrow) * 64 + rk]);
      #pragma unroll
      for (int nj = 0; nj < 4; ++nj)
        b[nj] = *reinterpret_cast<const bf16x8*>(&Br[(wc * 64 + nj * 16 + lrow) * 64 + rk]);
      #pragma unroll
      for (int mi = 0; mi < 4; ++mi)
        #pragma unroll
        for (int nj = 0; nj < 4; ++nj)
          acc[mi][nj] = __builtin_amdgcn_mfma_f32_16x16x32_bf16(a[mi], b[nj], acc[mi][nj], 0, 0, 0);
    }
  };

  STAGE(As0, Bs0, 0);
  #pragma unroll
  for (int i = 0; i < 8; ++i) {
    STAGE(As1, Bs1, i * 128 + 64);
    asm volatile("s_waitcnt vmcnt(8)" ::: "memory");
    __builtin_amdgcn_s_barrier();
    COMPUTE(As0, Bs0);
    __builtin_amdgcn_s_barrier();
    if (i < 7) {
      STAGE(As0, Bs0, i * 128 + 128);
      asm volatile("s_waitcnt vmcnt(8)" ::: "memory");
    } else {
      asm volatile("s_waitcnt vmcnt(0)" ::: "memory");
    }
    __builtin_amdgcn_s_barrier();
    COMPUTE(As1, Bs1);
    __builtin_amdgcn_s_barrier();
  }

  const int orow = lhi * 4, ocol = lrow;
  #pragma unroll
  for (int mi = 0; mi < 4; ++mi) {
    #pragma unroll
    for (int nj = 0; nj < 4; ++nj) {
      int gcol = n0 + wc * 64 + nj * 16 + ocol;
      float bv = bias[gcol];
      #pragma unroll
      for (int r = 0; r < 4; ++r) {
        int grow = m0 + wr * 64 + mi * 16 + orow + r;
        Cb[(size_t)grow * DM + gcol] = f2bf(acc[mi][nj][r] + bv);
      }
    }
  }
}

// ---------------- hidden kernel: H[assign][64] = silu(enc @ U_e^T) * w ----------------
__global__ __launch_bounds__(256) void k_hidden(
    const u16* __restrict__ Enc, const u16* __restrict__ Ub,
    const int* __restrict__ offs_e, const int* __restrict__ th_exp,
    const int* __restrict__ th_loc, const int* __restrict__ n_th,
    const int* __restrict__ e_tok, const float* __restrict__ e_w,
    u16* __restrict__ Hws) {
  const int bswz = (blockIdx.x & 7) * (GRID_HID >> 3) + (blockIdx.x >> 3);
  if (bswz >= n_th[0]) return;
  const int e = th_exp[bswz];
  const int loc0 = th_loc[bswz];
  const int base = offs_e[e];
  const int cnt = offs_e[e + 1] - base;
  const int tid = threadIdx.x;
  const int lane = tid & 63, wave = tid >> 6;
  const int lrow = lane & 15;
  const int lkb = (lane >> 4) * 16;  // byte offset of k-chunk within 64B

  __shared__ float s_ew[HT];
  __shared__ __align__(16) u16 Us[64 * 512];  // 64 KB: one K-half of U_e
  if (tid < HT) {
    int i = loc0 + tid;
    s_ew[tid] = (i < cnt) ? e_w[base + i] : 0.0f;
  }

  const u16* aP[2];
  #pragma unroll
  for (int mi = 0; mi < 2; ++mi) {
    int ridx = loc0 + wave * 32 + mi * 16 + lrow;
    int v = ridx < cnt;
    int tok = e_tok[base + (v ? ridx : 0)];
    aP[mi] = Enc + (size_t)tok * DM + (lane >> 4) * 8;
  }

  f32x4 acc[2][4];
  #pragma unroll
  for (int i = 0; i < 2; ++i)
    #pragma unroll
    for (int j = 0; j < 4; ++j) acc[i][j] = (f32x4){0.f, 0.f, 0.f, 0.f};

  const char* Ue = (const char*)(Ub + (size_t)e * RK * DM);  // row stride 2048 B

  for (int half = 0; half < 2; ++half) {
    __syncthreads();
    #pragma unroll
    for (int it = 0; it < 16; ++it) {
      int D = (tid + it * 256) * 16;
      int row = D >> 10, bo = D & 1023;
      int sbo = bo ^ ((row & 7) << 4);
      gload_lds16(Ue + (size_t)row * 2048 + half * 1024 + sbo, ((char*)Us) + D);
    }
    __syncthreads();
    #pragma unroll 4
    for (int step = 0; step < 16; ++step) {
      const int k0 = half * 512 + step * 32;
      bf16x8 b[4];
      #pragma unroll
      for (int nj = 0; nj < 4; ++nj) {
        int n = nj * 16 + lrow;
        int bofs = n * 1024 + ((step * 64 + lkb) ^ ((n & 7) << 4));
        b[nj] = *reinterpret_cast<const bf16x8*>(((const char*)Us) + bofs);
      }
      bf16x8 a0 = *reinterpret_cast<const bf16x8*>(aP[0] + k0);
      bf16x8 a1 = *reinterpret_cast<const bf16x8*>(aP[1] + k0);
      #pragma unroll
      for (int nj = 0; nj < 4; ++nj) {
        acc[0][nj] = __builtin_amdgcn_mfma_f32_16x16x32_bf16(a0, b[nj], acc[0][nj], 0, 0, 0);
        acc[1][nj] = __builtin_amdgcn_mfma_f32_16x16x32_bf16(a1, b[nj], acc[1][nj], 0, 0, 0);
      }
    }
  }

  #pragma unroll
  for (int mi = 0; mi < 2; ++mi)
    #pragma unroll
    for (int nj = 0; nj < 4; ++nj)
      #pragma unroll
      for (int rr = 0; rr < 4; ++rr) {
        int rloc = wave * 32 + mi * 16 + (lane >> 4) * 4 + rr;
        if (loc0 + rloc < cnt) {
          float z = acc[mi][nj][rr];
          float h = z / (1.0f + expf(-z)) * s_ew[rloc];
          Hws[(size_t)(base + loc0 + rloc) * RK + nj * 16 + (lane & 15)] = f2bf(h);
        }
      }
}

// ---------------- combine kernel: Out[tok] = enc + V0 @ H0 + V1 @ H1 ----------------
// Grid = tiles x 4 d-chunks. T14: enc gathers issued up front, consumed in epilogue.
__global__ __launch_bounds__(256) void k_combine(
    const u16* __restrict__ Enc, const u16* __restrict__ Vb,
    const u16* __restrict__ Hws, const int* __restrict__ offs_p,
    const int* __restrict__ tp_pair, const int* __restrict__ tp_loc,
    const int* __restrict__ n_tp, const int* __restrict__ a_tok,
    const int* __restrict__ a_h0, const int* __restrict__ a_h1,
    float* __restrict__ Out) {
  const int bswz = (blockIdx.x & 7) * (GRID_CMB >> 3) + (blockIdx.x >> 3);
  const int t = bswz >> 2;
  const int p = bswz & 3;
  if (t >= n_tp[0]) return;
  const int pid = tp_pair[t];
  const int pe0 = pid >> 4, pe1 = pid & 15;
  const int base = offs_p[pid];
  const int cnt = offs_p[pid + 1] - base;
  const int loc0 = tp_loc[t];
  const int tid = threadIdx.x;
  const int lane = tid & 63, wave = tid >> 6;

  __shared__ int s_tok[TPT];
  __shared__ int s_h0[TPT];
  __shared__ int s_h1[TPT];
  __shared__ int s_val[TPT];
  if (tid < TPT) {
    int idx = loc0 + tid;
    int v = idx < cnt;
    int pp = base + (v ? idx : 0);
    s_val[tid] = v;
    s_tok[tid] = a_tok[pp];
    s_h0[tid] = a_h0[pp];
    s_h1[tid] = a_h1[pp];
  }
  __syncthreads();

  const int lrow = lane & 15, lk = (lane >> 4) * 8;
  const int col0 = p * 256 + wave * 64;

  // H fragments (scattered L2 gathers)
  bf16x8 hb[4][4];  // [kk][tf]
  #pragma unroll
  for (int kk = 0; kk < 4; ++kk)
    #pragma unroll
    for (int tf = 0; tf < 4; ++tf) {
      int tok = tf * 16 + lrow;
      int hidx = (kk < 2) ? s_h0[tok] : s_h1[tok];
      hb[kk][tf] = *reinterpret_cast<const bf16x8*>(
          Hws + (size_t)hidx * RK + (kk & 1) * 32 + lk);
    }

  // T14: enc prefetch — issued before the V/MFMA phase, consumed in epilogue
  ushort4 encv[4][4];  // [mi][tf]
  #pragma unroll
  for (int mi = 0; mi < 4; ++mi)
    #pragma unroll
    for (int tf = 0; tf < 4; ++tf) {
      int tok = tf * 16 + (lane & 15);
      int d = col0 + mi * 16 + (lane >> 4) * 4;
      encv[mi][tf] = *reinterpret_cast<const ushort4*>(Enc + (size_t)s_tok[tok] * DM + d);
    }

  const u16* V0 = Vb + (size_t)pe0 * DM * RK;
  const u16* V1 = Vb + (size_t)pe1 * DM * RK;

  f32x4 acc2[4][4];  // [mi][tf]
  #pragma unroll
  for (int i = 0; i < 4; ++i)
    #pragma unroll
    for (int j = 0; j < 4; ++j) acc2[i][j] = (f32x4){0.f, 0.f, 0.f, 0.f};

  #pragma unroll
  for (int kk = 0; kk < 4; ++kk) {
    const u16* Vsel = (kk < 2) ? V0 : V1;
    const int kof = (kk & 1) * 32 + lk;
    #pragma unroll
    for (int mi = 0; mi < 4; ++mi) {
      int d = col0 + mi * 16 + lrow;
      bf16x8 va = *reinterpret_cast<const bf16x8*>(Vsel + (size_t)d * RK + kof);
      #pragma unroll
      for (int tf = 0; tf < 4; ++tf)
        acc2[mi][tf] = __builtin_amdgcn_mfma_f32_16x16x32_bf16(va, hb[kk][tf], acc2[mi][tf], 0, 0, 0);
    }
  }

  #pragma unroll
  for (int mi = 0; mi < 4; ++mi)
    #pragma unroll
    for (int tf = 0; tf < 4; ++tf) {
      int tok = tf * 16 + (lane & 15);
      if (!s_val[tok]) continue;
      int d = col0 + mi * 16 + (lane >> 4) * 4;
      size_t ro = (size_t)s_tok[tok] * DM + d;
      ushort4 ev = encv[mi][tf];
      float4 o;
      o.x = acc2[mi][tf][0] + bf2f(ev.x);
      o.y = acc2[mi][tf][1] + bf2f(ev.y);
      o.z = acc2[mi][tf][2] + bf2f(ev.z);
      o.w = acc2[mi][tf][3] + bf2f(ev.w);
      *reinterpret_cast<float4*>(Out + ro) = o;
    }
}

// ---------------- host launch ----------------
extern "C" void kernel_launch(void* const* d_in, const int* in_sizes, int n_in,
                              void* d_out, int out_size, void* d_ws, size_t ws_size,
                              hipStream_t stream) {
  const float* x = (const float*)d_in[0];
  const float* We = (const float*)d_in[1];
  const float* be = (const float*)d_in[2];
  const float* Wg = (const float*)d_in[3];
  const float* U = (const float*)d_in[4];
  const float* V = (const float*)d_in[5];
  const float* gamma = (const float*)d_in[6];
  float* Out = (float*)d_out;

  char* ws = (char*)d_ws;
  size_t off = 0;
  auto alloc = [&](size_t bytes) -> void* {
    void* p = ws + off;
    off += (bytes + 255) & ~(size_t)255;
    return p;
  };
  u16* x_bf   = (u16*)alloc((size_t)B_TOK * DM * 2);
  u16* enc_bf = (u16*)alloc((size_t)B_TOK * DM * 2);
  u16* We_bf  = (u16*)alloc((size_t)DM * DM * 2);
  u16* U_bf   = (u16*)alloc((size_t)NEXP * RK * DM * 2);
  u16* V_bf   = (u16*)alloc((size_t)NEXP * DM * RK * 2);
  u16* Hws    = (u16*)alloc(((size_t)2 * B_TOK + HT) * RK * 2);
  double* Wpart = (double*)alloc((size_t)4 * NEXP * DM * 8);
  float* Wgeff = (float*)alloc((size_t)NEXP * DM * 4);
  float* gbias = (float*)alloc(NEXP * 4);
  int* tk_pid  = (int*)alloc((size_t)B_TOK * 4);
  float* tk_w0 = (float*)alloc((size_t)B_TOK * 4);
  float* tk_w1 = (float*)alloc((size_t)B_TOK * 4);
  int* counts_p = (int*)alloc(NPAIR * 4);
  int* counts_e = (int*)alloc(NEXP * 4);
  int* offs_p   = (int*)alloc((NPAIR + 1) * 4);
  int* curs_p   = (int*)alloc(NPAIR * 4);
  int* offs_e   = (int*)alloc((NEXP + 1) * 4);
  int* curs_e   = (int*)alloc(NEXP * 4);
  int* tp_pair  = (int*)alloc(MAXTILE * 4);
  int* tp_loc   = (int*)alloc(MAXTILE * 4);
  int* n_tp     = (int*)alloc(256);
  int* th_exp   = (int*)alloc(MAXTILE * 4);
  int* th_loc   = (int*)alloc(MAXTILE * 4);
  int* n_th     = (int*)alloc(256);
  int* a_tok   = (int*)alloc((size_t)B_TOK * 4);
  int* a_h0    = (int*)alloc((size_t)B_TOK * 4);
  int* a_h1    = (int*)alloc((size_t)B_TOK * 4);
  int* e_tok   = (int*)alloc(((size_t)2 * B_TOK + HT) * 4);
  float* e_w   = (float*)alloc(((size_t)2 * B_TOK + HT) * 4);
  (void)ws_size; (void)in_sizes; (void)n_in; (void)out_size;

  hipMemsetAsync(counts_p, 0, NPAIR * 4, stream);
  hipMemsetAsync(counts_e, 0, NEXP * 4, stream);

  k_prep<<<1024, 256, 0, stream>>>(We, We_bf, U, U_bf, V, V_bf, Wg, We, Wpart);
  k_wgred<<<dim3(4, 16), 256, 0, stream>>>(Wpart, Wg, be, Wgeff, gbias);
  k_gating<<<B_TOK / GT, 256, 0, stream>>>(x, x_bf, Wgeff, gbias, gamma,
                                           tk_pid, tk_w0, tk_w1, counts_p, counts_e);
  k_scan<<<1, NPAIR, 0, stream>>>(counts_p, counts_e, offs_p, curs_p, offs_e, curs_e,
                                  tp_pair, tp_loc, n_tp, th_exp, th_loc, n_th);
  k_scatter<<<B_TOK / 256, 256, 0, stream>>>(tk_pid, tk_w0, tk_w1, curs_p, curs_e,
                                             a_tok, a_h0, a_h1, e_tok, e_w);
  k_encoder<<<dim3(DM / 128, B_TOK / 128), 256, 0, stream>>>(x_bf, We_bf, be, enc_bf);
  k_hidden<<<GRID_HID, 256, 0, stream>>>(enc_bf, U_bf, offs_e, th_exp, th_loc, n_th,
                                         e_tok, e_w, Hws);
  k_combine<<<GRID_CMB, 256, 0, stream>>>(enc_bf, V_bf, Hws, offs_p, tp_pair, tp_loc,
                                          n_tp, a_tok, a_h0, a_h1, Out);
}